// Round 11
// baseline (302.443 us; speedup 1.0000x reference)
//
#include <hip/hip_runtime.h>

#define HID 128
#define C2 256   // HEADS*HID
#define NEG 0.2f

typedef __bf16 v8bf __attribute__((ext_vector_type(8)));
typedef float  v4f  __attribute__((ext_vector_type(4)));
typedef float  v2f  __attribute__((ext_vector_type(2)));
typedef unsigned short us8 __attribute__((ext_vector_type(8)));

__device__ __forceinline__ float bf2f(unsigned short u) {
    union { float f; unsigned int i; } v; v.i = ((unsigned int)u) << 16; return v.f;
}
__device__ __forceinline__ unsigned short f2bf(float f) {
    union { float f; unsigned int i; } v; v.f = f;
    unsigned int r = v.i + 0x7FFFu + ((v.i >> 16) & 1u);
    return (unsigned short)(r >> 16);
}
__device__ __forceinline__ unsigned char f2fp8(float f) {
    return (unsigned char)(__builtin_amdgcn_cvt_pk_fp8_f32(f, f, 0, false) & 0xFF);
}
__device__ __forceinline__ float lrelu(float x) { return x > 0.f ? x : NEG * x; }

// ---------------- pack W[K,N] fp32 -> bf16 MFMA-B-fragment order ----------------
__global__ __launch_bounds__(256) void packB(const float* __restrict__ W,
                                             unsigned short* __restrict__ out,
                                             int K, int N) {
    int idx = blockIdx.x * 256 + threadIdx.x;
    int ksteps = K >> 5;
    int total = (N >> 4) * ksteps * 64;
    if (idx >= total) return;
    int lane = idx & 63;
    int rest = idx >> 6;
    int nt = rest / ksteps, k0 = rest - nt * ksteps;
    int n = nt * 16 + (lane & 15);
    int kb = k0 * 32 + (lane >> 4) * 8;
    us8 v;
#pragma unroll
    for (int j = 0; j < 8; ++j) v[j] = f2bf(W[(size_t)(kb + j) * N + n]);
    *(us8*)(out + (size_t)idx * 8) = v;
}

// ---------------- CSR build (edges only; self-loops handled in agg) ----------------
// hist + rank: one atomic pass; rank[i] = position of edge i within its dst segment
__global__ void hist_rank_kernel(const int* __restrict__ ei, int* __restrict__ cnt,
                                 int* __restrict__ rank, int E) {
    int i = blockIdx.x * 256 + threadIdx.x;
    if (i >= E) return;
    int d = ei[E + i];
    rank[i] = atomicAdd(&cnt[d], 1);
}

__global__ __launch_bounds__(256) void scanA(const int* __restrict__ cnt, int* __restrict__ rs,
                                             int* __restrict__ part, int N) {
    __shared__ int s[256];
    int t = threadIdx.x, i = blockIdx.x * 256 + t;
    int v = (i < N) ? cnt[i] : 0;
    s[t] = v; __syncthreads();
    for (int off = 1; off < 256; off <<= 1) {
        int x = (t >= off) ? s[t - off] : 0;
        __syncthreads();
        s[t] += x;
        __syncthreads();
    }
    if (i < N) rs[i] = s[t] - v;
    if (t == 255) part[blockIdx.x] = s[255];
}

__global__ __launch_bounds__(256) void scanB(int* __restrict__ part, int n) {
    __shared__ int s[256];
    int t = threadIdx.x;
    int v = (t < n) ? part[t] : 0;
    s[t] = v; __syncthreads();
    for (int off = 1; off < 256; off <<= 1) {
        int x = (t >= off) ? s[t - off] : 0;
        __syncthreads();
        s[t] += x;
        __syncthreads();
    }
    if (t < n) part[t] = s[t] - v;
}

__global__ void scanC(int* __restrict__ rs, const int* __restrict__ part, int N, int E) {
    int i = blockIdx.x * 256 + threadIdx.x;
    if (i < N) rs[i] += part[blockIdx.x];
    if (i == 0) rs[N] = E;
}

// atomic-free scatter: csr[rs[d] + rank[i]] = src
__global__ void scatter_kernel(const int* __restrict__ ei, const int* __restrict__ rs,
                               const int* __restrict__ rank, int* __restrict__ csr, int E) {
    int i = blockIdx.x * 256 + threadIdx.x;
    if (i >= E) return;
    int s = ei[i], d = ei[E + i];
    csr[rs[d] + rank[i]] = s;
}

// ---------------- GEMM (layers 1,2): LDS-staged B, fused alpha dots, fp8 h out ----------------
// block = 4 waves, one n-group g, 8 m-tiles (G=2/wave). B staged in 32 KB chunks (kc=4 ksteps).
template<bool AFP32, int G>
__global__ __launch_bounds__(256) void gemm_alpha(const void* __restrict__ Av,
                                                  const unsigned short* __restrict__ Bp,
                                                  const float* __restrict__ asrc,
                                                  const float* __restrict__ adst,
                                                  float* __restrict__ asd,
                                                  unsigned char* __restrict__ C,
                                                  int M, int N, int K) {
    const int kc = 4;
    int ksteps = K >> 5;
    int ngrp = N >> 7;
    int mtiles = M >> 4;
    int bm = 4 * G;
    int g = blockIdx.x % ngrp, mblk = blockIdx.x / ngrp;
    int wv = threadIdx.x >> 6, lane = threadIdx.x & 63;
    int l16 = lane & 15, quad = lane >> 4;
    int mt0 = mblk * bm + wv * G;

    __shared__ unsigned short Bs[8 * kc * 512];   // 32 KB

    int mrow[G];
#pragma unroll
    for (int gi = 0; gi < G; ++gi) {
        int mt = mt0 + gi;
        mrow[gi] = (mt < mtiles ? mt : mtiles - 1) * 16 + l16;
    }

    const us8* srcB = (const us8*)Bp + (size_t)(g * 8) * ksteps * 64;
    v4f acc[G][8];
#pragma unroll
    for (int gi = 0; gi < G; ++gi)
#pragma unroll
        for (int t = 0; t < 8; ++t) acc[gi][t] = (v4f){0, 0, 0, 0};

    for (int c0 = 0; c0 < ksteps; c0 += kc) {
        __syncthreads();
        for (int f = threadIdx.x; f < 8 * kc * 64; f += 256) {
            int t = f >> 8;               // f / (kc*64)
            int rem = f & 255;
            int kr = rem >> 6, l = rem & 63;
            ((us8*)Bs)[f] = srcB[((size_t)t * ksteps + c0 + kr) * 64 + l];
        }
        __syncthreads();
        for (int kr = 0; kr < kc; ++kr) {
            int k0 = c0 + kr;
            v8bf a[G];
            if (AFP32) {
                const float* A = (const float*)Av;
#pragma unroll
                for (int gi = 0; gi < G; ++gi) {
                    const float* p = A + (size_t)mrow[gi] * K + k0 * 32 + quad * 8;
                    float4 u0 = *(const float4*)p, u1 = *(const float4*)(p + 4);
                    a[gi][0]=(__bf16)u0.x; a[gi][1]=(__bf16)u0.y; a[gi][2]=(__bf16)u0.z; a[gi][3]=(__bf16)u0.w;
                    a[gi][4]=(__bf16)u1.x; a[gi][5]=(__bf16)u1.y; a[gi][6]=(__bf16)u1.z; a[gi][7]=(__bf16)u1.w;
                }
            } else {
                const unsigned short* A = (const unsigned short*)Av;
#pragma unroll
                for (int gi = 0; gi < G; ++gi)
                    a[gi] = *(const v8bf*)(A + (size_t)mrow[gi] * K + k0 * 32 + quad * 8);
            }
#pragma unroll
            for (int t = 0; t < 8; ++t) {
                v8bf bfr = ((const v8bf*)Bs)[(t * kc + kr) * 64 + lane];
#pragma unroll
                for (int gi = 0; gi < G; ++gi)
                    acc[gi][t] = __builtin_amdgcn_mfma_f32_16x16x32_bf16(a[gi], bfr, acc[gi][t], 0, 0, 0);
            }
        }
    }

    int n0 = g << 7;
    float sv[8], dv[8];
#pragma unroll
    for (int t = 0; t < 8; ++t) {
        int col = n0 + t * 16 + l16;
        sv[t] = asrc[col];
        dv[t] = adst[col];
    }
#pragma unroll
    for (int gi = 0; gi < G; ++gi) {
        int mt = mt0 + gi;
        if (mt >= mtiles) break;
        int row0 = mt * 16 + quad * 4;
#pragma unroll
        for (int r = 0; r < 4; ++r) {
            float sa = 0.f, sd = 0.f;
#pragma unroll
            for (int t = 0; t < 8; ++t) {
                int col = n0 + t * 16 + l16;
                float hv = acc[gi][t][r];
                C[(size_t)(row0 + r) * N + col] = f2fp8(hv);
                sa += hv * sv[t];
                sd += hv * dv[t];
            }
#pragma unroll
            for (int off = 8; off; off >>= 1) {
                sa += __shfl_xor(sa, off);
                sd += __shfl_xor(sd, off);
            }
            if (l16 == 0) {
                int row = row0 + r;
                asd[(size_t)row * 4 + g]     = sa;
                asd[(size_t)row * 4 + 2 + g] = sd;
            }
        }
    }
}

// ---------------- single-pass agg over fp8 h; one wave per dest; self-loop analytic ----------------
__global__ __launch_bounds__(256) void agg_kernel(const int* __restrict__ rs,
                                                  const int* __restrict__ csr,
                                                  const unsigned char* __restrict__ h,
                                                  const float* __restrict__ asd,
                                                  const float* __restrict__ bias,
                                                  unsigned short* __restrict__ out, int N) {
    int d = blockIdx.x * 4 + (threadIdx.x >> 6);
    if (d >= N) return;
    int lane = threadIdx.x & 63;
    int beg = rs[d], end = rs[d + 1];
    int e2 = lane >> 5;
    int sub = lane & 31;
    int head = sub >> 4;
    float adh = asd[(size_t)d * 4 + 2 + head];
    int cbase = sub * 8;
    const unsigned char* hc = h + cbase;
    v2f a01 = {0, 0}, a23 = {0, 0}, a45 = {0, 0}, a67 = {0, 0};
    float den = 0.f;
#pragma unroll 2
    for (int i = beg; i < end; i += 2) {
        int ei = i + e2;
        bool valid = ei < end;
        int s = csr[valid ? ei : end - 1];
        float e = lrelu(asd[(size_t)s * 4 + head] + adh);
        float wgt = valid ? __expf(e) : 0.f;
        den += wgt;
        uint2 u = *(const uint2*)(hc + (size_t)s * C2);
        v2f w2 = {wgt, wgt};
        a01 += w2 * __builtin_amdgcn_cvt_pk_f32_fp8(u.x, false);
        a23 += w2 * __builtin_amdgcn_cvt_pk_f32_fp8(u.x, true);
        a45 += w2 * __builtin_amdgcn_cvt_pk_f32_fp8(u.y, false);
        a67 += w2 * __builtin_amdgcn_cvt_pk_f32_fp8(u.y, true);
    }
    float a[8] = {a01.x, a01.y, a23.x, a23.y, a45.x, a45.y, a67.x, a67.y};
#pragma unroll
    for (int j = 0; j < 8; ++j) a[j] += __shfl_xor(a[j], 32);
    den += __shfl_xor(den, 32);
    if (e2 == 0) {
        // self-loop term (src = d), not present in csr
        float wS = __expf(lrelu(asd[(size_t)d * 4 + head] + adh));
        uint2 u = *(const uint2*)(hc + (size_t)d * C2);
        v2f p0 = __builtin_amdgcn_cvt_pk_f32_fp8(u.x, false);
        v2f p1 = __builtin_amdgcn_cvt_pk_f32_fp8(u.x, true);
        v2f p2 = __builtin_amdgcn_cvt_pk_f32_fp8(u.y, false);
        v2f p3 = __builtin_amdgcn_cvt_pk_f32_fp8(u.y, true);
        a[0] += wS * p0.x; a[1] += wS * p0.y;
        a[2] += wS * p1.x; a[3] += wS * p1.y;
        a[4] += wS * p2.x; a[5] += wS * p2.y;
        a[6] += wS * p3.x; a[7] += wS * p3.y;
        float rden = 1.f / (den + wS + 1e-16f);
        us8 o;
#pragma unroll
        for (int j = 0; j < 8; ++j) o[j] = f2bf(fmaxf(a[j] * rden + bias[cbase + j], 0.f));
        *(us8*)(out + (size_t)d * C2 + cbase) = o;
    }
}

// ---------------- post-MLP fused, LDS-staged B: t = A@Wp1 + bp1; out = sigmoid(t.Wp2 + bp2) ----------------
template<int G>
__global__ __launch_bounds__(256) void gemm_final(const unsigned short* __restrict__ A,
                                                  const unsigned short* __restrict__ Bp,
                                                  const float* __restrict__ bp1,
                                                  const float* __restrict__ wp2,
                                                  const float* __restrict__ bp2,
                                                  float* __restrict__ out,
                                                  int M, int K) {
    const int kc = 4;
    int ksteps = K >> 5;                 // 8
    int mtiles = M >> 4;
    int bm = 4 * G;
    int mblk = blockIdx.x;
    int wv = threadIdx.x >> 6, lane = threadIdx.x & 63;
    int l16 = lane & 15, quad = lane >> 4;
    int mt0 = mblk * bm + wv * G;

    __shared__ unsigned short Bs[8 * kc * 512];   // 32 KB

    int mrow[G];
#pragma unroll
    for (int gi = 0; gi < G; ++gi) {
        int mt = mt0 + gi;
        mrow[gi] = (mt < mtiles ? mt : mtiles - 1) * 16 + l16;
    }

    const us8* srcB = (const us8*)Bp;
    v4f acc[G][8];
#pragma unroll
    for (int gi = 0; gi < G; ++gi)
#pragma unroll
        for (int t = 0; t < 8; ++t) acc[gi][t] = (v4f){0, 0, 0, 0};

    for (int c0 = 0; c0 < ksteps; c0 += kc) {
        __syncthreads();
        for (int f = threadIdx.x; f < 8 * kc * 64; f += 256) {
            int t = f >> 8;
            int rem = f & 255;
            int kr = rem >> 6, l = rem & 63;
            ((us8*)Bs)[f] = srcB[((size_t)t * ksteps + c0 + kr) * 64 + l];
        }
        __syncthreads();
        for (int kr = 0; kr < kc; ++kr) {
            int k0 = c0 + kr;
            v8bf a[G];
#pragma unroll
            for (int gi = 0; gi < G; ++gi)
                a[gi] = *(const v8bf*)(A + (size_t)mrow[gi] * K + k0 * 32 + quad * 8);
#pragma unroll
            for (int t = 0; t < 8; ++t) {
                v8bf bfr = ((const v8bf*)Bs)[(t * kc + kr) * 64 + lane];
#pragma unroll
                for (int gi = 0; gi < G; ++gi)
                    acc[gi][t] = __builtin_amdgcn_mfma_f32_16x16x32_bf16(a[gi], bfr, acc[gi][t], 0, 0, 0);
            }
        }
    }
    float wv8[8], bv[8];
#pragma unroll
    for (int t = 0; t < 8; ++t) {
        int col = t * 16 + l16;
        wv8[t] = wp2[col];
        bv[t] = bp1[col];
    }
    float bias2 = bp2[0];
#pragma unroll
    for (int gi = 0; gi < G; ++gi) {
        int mt = mt0 + gi;
        if (mt >= mtiles) break;
        int row0 = mt * 16 + quad * 4;
#pragma unroll
        for (int r = 0; r < 4; ++r) {
            float s = 0.f;
#pragma unroll
            for (int t = 0; t < 8; ++t) s += (acc[gi][t][r] + bv[t]) * wv8[t];
#pragma unroll
            for (int off = 8; off; off >>= 1) s += __shfl_xor(s, off);
            if (l16 == 0) {
                float xv = s + bias2;
                out[row0 + r] = 1.f / (1.f + __expf(-xv));
            }
        }
    }
}

extern "C" void kernel_launch(void* const* d_in, const int* in_sizes, int n_in,
                              void* d_out, int out_size, void* d_ws, size_t ws_size,
                              hipStream_t stream) {
    const float* x   = (const float*)d_in[0];
    const int*   ei  = (const int*)d_in[1];
    const float* W1  = (const float*)d_in[2];
    const float* as1 = (const float*)d_in[3];
    const float* ad1 = (const float*)d_in[4];
    const float* b1  = (const float*)d_in[5];
    const float* W2  = (const float*)d_in[6];
    const float* as2 = (const float*)d_in[7];
    const float* ad2 = (const float*)d_in[8];
    const float* b2  = (const float*)d_in[9];
    const float* Wp1 = (const float*)d_in[10];
    const float* bp1 = (const float*)d_in[11];
    const float* Wp2 = (const float*)d_in[12];
    const float* bp2 = (const float*)d_in[13];
    float* out = (float*)d_out;

    int NN = in_sizes[0] / HID;   // 50000
    int E  = in_sizes[1] / 2;     // 800000

    char* ws = (char*)d_ws;
    size_t off = 0;
    auto alloc = [&](size_t bytes) -> char* {
        char* p = ws + off;
        off += (bytes + 255) & ~(size_t)255;
        return p;
    };
    unsigned char*  bufH = (unsigned char*)alloc((size_t)NN * C2);       // h, fp8 e4m3
    unsigned short* bufO = (unsigned short*)alloc((size_t)NN * C2 * 2);  // agg out, bf16
    float* asd = (float*)alloc((size_t)NN * 4 * sizeof(float));
    int* rs    = (int*)alloc((size_t)(NN + 1) * 4);
    int* cnt   = (int*)alloc((size_t)NN * 4);
    int* rank  = (int*)alloc((size_t)E * 4);
    int* csr   = (int*)alloc((size_t)E * 4);
    int* part  = (int*)alloc(1024);
    unsigned short* W1p  = (unsigned short*)alloc((size_t)HID * C2 * 2);  // packed
    unsigned short* W2p  = (unsigned short*)alloc((size_t)C2 * C2 * 2);
    unsigned short* Wp1p = (unsigned short*)alloc((size_t)C2 * HID * 2);

    int nchunk = (NN + 255) / 256;
    int eblk   = (E + 255) / 256;

    // weight staging (bf16 + MFMA-fragment packing)
    packB<<<(HID * C2 / 8 + 255) / 256, 256, 0, stream>>>(W1, W1p, HID, C2);
    packB<<<(C2 * C2 / 8 + 255) / 256, 256, 0, stream>>>(W2, W2p, C2, C2);
    packB<<<(C2 * HID / 8 + 255) / 256, 256, 0, stream>>>(Wp1, Wp1p, C2, HID);

    // CSR build (edges only; self-loops analytic in agg)
    hipMemsetAsync(cnt, 0, (size_t)NN * 4, stream);
    hist_rank_kernel<<<eblk, 256, 0, stream>>>(ei, cnt, rank, E);
    scanA<<<nchunk, 256, 0, stream>>>(cnt, rs, part, NN);
    scanB<<<1, 256, 0, stream>>>(part, nchunk);
    scanC<<<nchunk, 256, 0, stream>>>(rs, part, NN, E);
    scatter_kernel<<<eblk, 256, 0, stream>>>(ei, rs, rank, csr, E);

    const int G = 2;
    int mtiles = NN / 16;                     // 3125
    int bm = 4 * G;                           // m-tiles per block
    int groups = (mtiles + bm - 1) / bm;      // 391
    int aggGrid = (NN + 3) / 4;

    // layer 1 (A = fp32 x, cvt in-register) + fused alpha dots
    gemm_alpha<true, G><<<groups * 2, 256, 0, stream>>>(x, W1p, as1, ad1, asd, bufH, NN, C2, HID);
    agg_kernel<<<aggGrid, 256, 0, stream>>>(rs, csr, bufH, asd, b1, bufO, NN);
    // layer 2
    gemm_alpha<false, G><<<groups * 2, 256, 0, stream>>>(bufO, W2p, as2, ad2, asd, bufH, NN, C2, C2);
    agg_kernel<<<aggGrid, 256, 0, stream>>>(rs, csr, bufH, asd, b2, bufO, NN);
    // post-MLP fully fused
    gemm_final<G><<<groups, 256, 0, stream>>>(bufO, Wp1p, bp1, Wp2, bp2, out, NN, C2);
}

// Round 12
// 287.799 us; speedup vs baseline: 1.0509x; 1.0509x over previous
//
#include <hip/hip_runtime.h>

#define HID 128
#define C2 256   // HEADS*HID
#define NEG 0.2f

typedef __bf16 v8bf __attribute__((ext_vector_type(8)));
typedef float  v4f  __attribute__((ext_vector_type(4)));
typedef float  v2f  __attribute__((ext_vector_type(2)));
typedef unsigned short us8 __attribute__((ext_vector_type(8)));

__device__ __forceinline__ float bf2f(unsigned short u) {
    union { float f; unsigned int i; } v; v.i = ((unsigned int)u) << 16; return v.f;
}
__device__ __forceinline__ unsigned short f2bf(float f) {
    union { float f; unsigned int i; } v; v.f = f;
    unsigned int r = v.i + 0x7FFFu + ((v.i >> 16) & 1u);
    return (unsigned short)(r >> 16);
}
__device__ __forceinline__ float lrelu(float x) { return x > 0.f ? x : NEG * x; }

// ---------------- prep: 3x packB + hist_rank fused ----------------
// packB new column mapping: tile tt covers cols n(tt,l16) = (tt>>3)*128 + l16*8 + (tt&7)
// -> epilogue lane bytes are 8 CONSECUTIVE cols (coalesced uint2 store).
__device__ __forceinline__ void packB_body(const float* __restrict__ W,
                                           unsigned short* __restrict__ out,
                                           int K, int N, int idx) {
    int ksteps = K >> 5;
    int total = (N >> 4) * ksteps * 64;
    if (idx >= total) return;
    int lane = idx & 63;
    int rest = idx >> 6;
    int tt = rest / ksteps, k0 = rest - tt * ksteps;
    int n = (tt >> 3) * 128 + (lane & 15) * 8 + (tt & 7);
    int kb = k0 * 32 + (lane >> 4) * 8;
    us8 v;
#pragma unroll
    for (int j = 0; j < 8; ++j) v[j] = f2bf(W[(size_t)(kb + j) * N + n]);
    *(us8*)(out + (size_t)idx * 8) = v;
}

__global__ __launch_bounds__(256) void prep_kernel(const float* __restrict__ W1, unsigned short* W1p,
                                                   const float* __restrict__ W2, unsigned short* W2p,
                                                   const float* __restrict__ Wp1, unsigned short* Wp1p,
                                                   const int* __restrict__ ei, int* __restrict__ cnt,
                                                   int* __restrict__ rank, int E,
                                                   int b1, int b2, int b3) {
    int b = blockIdx.x;
    if (b < b1) { packB_body(W1, W1p, HID, C2, b * 256 + threadIdx.x); return; }
    b -= b1;
    if (b < b2) { packB_body(W2, W2p, C2, C2, b * 256 + threadIdx.x); return; }
    b -= b2;
    if (b < b3) { packB_body(Wp1, Wp1p, C2, HID, b * 256 + threadIdx.x); return; }
    b -= b3;
    int i = b * 256 + threadIdx.x;
    if (i >= E) return;
    int d = ei[E + i];
    rank[i] = atomicAdd(&cnt[d], 1);
}

// ---------------- scans ----------------
__global__ __launch_bounds__(256) void scanA(const int* __restrict__ cnt, int* __restrict__ rs,
                                             int* __restrict__ part, int N) {
    __shared__ int s[256];
    int t = threadIdx.x, i = blockIdx.x * 256 + t;
    int v = (i < N) ? cnt[i] : 0;
    s[t] = v; __syncthreads();
    for (int off = 1; off < 256; off <<= 1) {
        int x = (t >= off) ? s[t - off] : 0;
        __syncthreads();
        s[t] += x;
        __syncthreads();
    }
    if (i < N) rs[i] = s[t] - v;
    if (t == 255) part[blockIdx.x] = s[255];
}

__global__ __launch_bounds__(256) void scanB(int* __restrict__ part, int n) {
    __shared__ int s[256];
    int t = threadIdx.x;
    int v = (t < n) ? part[t] : 0;
    s[t] = v; __syncthreads();
    for (int off = 1; off < 256; off <<= 1) {
        int x = (t >= off) ? s[t - off] : 0;
        __syncthreads();
        s[t] += x;
        __syncthreads();
    }
    if (t < n) part[t] = s[t] - v;
}

__global__ void scanC(int* __restrict__ rs, const int* __restrict__ part, int N, int E) {
    int i = blockIdx.x * 256 + threadIdx.x;
    if (i < N) rs[i] += part[blockIdx.x];
    if (i == 0) rs[N] = E;
}

// ---------------- GEMM (layers 1,2): fused alpha dots + coalesced fp8 store ----------------
// blocks [0, gemmBlocks): gemm; blocks [gemmBlocks, +scatBlocks): atomic-free scatter (layer1 only).
template<bool AFP32, int G>
__global__ __launch_bounds__(256) void gemm_alpha(const void* __restrict__ Av,
                                                  const unsigned short* __restrict__ Bp,
                                                  const float* __restrict__ asrc,
                                                  const float* __restrict__ adst,
                                                  float* __restrict__ asd,
                                                  unsigned char* __restrict__ C,
                                                  int M, int N, int K, int gemmBlocks,
                                                  const int* __restrict__ ei,
                                                  const int* __restrict__ rs,
                                                  const int* __restrict__ rank,
                                                  int* __restrict__ csr, int E) {
    if (blockIdx.x >= gemmBlocks) {
        int i = (blockIdx.x - gemmBlocks) * 256 + threadIdx.x;
        if (i < E) {
            int s = ei[i], d = ei[E + i];
            csr[rs[d] + rank[i]] = s;
        }
        return;
    }
    int ksteps = K >> 5;
    int ngrp = N >> 7;
    int mtiles = M >> 4;
    int w = (blockIdx.x << 2) + (threadIdx.x >> 6);
    int groups = (mtiles + G - 1) / G;
    int mp = w / ngrp, g = w - mp * ngrp;
    if (mp >= groups) return;
    int lane = threadIdx.x & 63;
    int l16 = lane & 15, quad = lane >> 4;
    int mt0 = mp * G;

    int mrow[G];
#pragma unroll
    for (int gi = 0; gi < G; ++gi) {
        int mt = mt0 + gi;
        mrow[gi] = (mt < mtiles ? mt : mtiles - 1) * 16 + l16;
    }

    const unsigned short* Bf = Bp + ((size_t)(g * 8) * ksteps << 9) + lane * 8;
    v4f acc[G][8];
#pragma unroll
    for (int gi = 0; gi < G; ++gi)
#pragma unroll
        for (int t = 0; t < 8; ++t) acc[gi][t] = (v4f){0, 0, 0, 0};

    for (int k0 = 0; k0 < ksteps; ++k0) {
        v8bf a[G];
        if (AFP32) {
            const float* A = (const float*)Av;
#pragma unroll
            for (int gi = 0; gi < G; ++gi) {
                const float* p = A + (size_t)mrow[gi] * K + k0 * 32 + quad * 8;
                float4 u0 = *(const float4*)p, u1 = *(const float4*)(p + 4);
                a[gi][0]=(__bf16)u0.x; a[gi][1]=(__bf16)u0.y; a[gi][2]=(__bf16)u0.z; a[gi][3]=(__bf16)u0.w;
                a[gi][4]=(__bf16)u1.x; a[gi][5]=(__bf16)u1.y; a[gi][6]=(__bf16)u1.z; a[gi][7]=(__bf16)u1.w;
            }
        } else {
            const unsigned short* A = (const unsigned short*)Av;
#pragma unroll
            for (int gi = 0; gi < G; ++gi)
                a[gi] = *(const v8bf*)(A + (size_t)mrow[gi] * K + k0 * 32 + quad * 8);
        }
#pragma unroll
        for (int t = 0; t < 8; ++t) {
            v8bf bfr = *(const v8bf*)(Bf + ((size_t)(t * ksteps + k0) << 9));
#pragma unroll
            for (int gi = 0; gi < G; ++gi)
                acc[gi][t] = __builtin_amdgcn_mfma_f32_16x16x32_bf16(a[gi], bfr, acc[gi][t], 0, 0, 0);
        }
    }

    int n0 = g << 7;
    int cb = n0 + l16 * 8;                // lane's 8 consecutive cols: cb + t
    float sv[8], dv[8];
#pragma unroll
    for (int t = 0; t < 8; ++t) {
        sv[t] = asrc[cb + t];
        dv[t] = adst[cb + t];
    }
#pragma unroll
    for (int gi = 0; gi < G; ++gi) {
        int mt = mt0 + gi;
        if (mt >= mtiles) break;
        int row0 = mt * 16 + quad * 4;
#pragma unroll
        for (int r = 0; r < 4; ++r) {
            float sa = 0.f, sd = 0.f;
#pragma unroll
            for (int t = 0; t < 8; ++t) {
                sa += acc[gi][t][r] * sv[t];
                sd += acc[gi][t][r] * dv[t];
            }
            unsigned int w0 = __builtin_amdgcn_cvt_pk_fp8_f32(acc[gi][0][r], acc[gi][1][r], 0, false);
            w0 = __builtin_amdgcn_cvt_pk_fp8_f32(acc[gi][2][r], acc[gi][3][r], w0, true);
            unsigned int w1 = __builtin_amdgcn_cvt_pk_fp8_f32(acc[gi][4][r], acc[gi][5][r], 0, false);
            w1 = __builtin_amdgcn_cvt_pk_fp8_f32(acc[gi][6][r], acc[gi][7][r], w1, true);
            *(uint2*)(C + (size_t)(row0 + r) * N + cb) = (uint2){w0, w1};
#pragma unroll
            for (int off = 8; off; off >>= 1) {
                sa += __shfl_xor(sa, off);
                sd += __shfl_xor(sd, off);
            }
            if (l16 == 0) {
                int row = row0 + r;
                asd[(size_t)row * 4 + g]     = sa;
                asd[(size_t)row * 4 + 2 + g] = sd;
            }
        }
    }
}

// ---------------- single-pass agg over fp8 h; one wave per dest; self-loop analytic ----------------
__global__ __launch_bounds__(256) void agg_kernel(const int* __restrict__ rs,
                                                  const int* __restrict__ csr,
                                                  const unsigned char* __restrict__ h,
                                                  const float* __restrict__ asd,
                                                  const float* __restrict__ bias,
                                                  unsigned short* __restrict__ out, int N) {
    int d = blockIdx.x * 4 + (threadIdx.x >> 6);
    if (d >= N) return;
    int lane = threadIdx.x & 63;
    int beg = rs[d], end = rs[d + 1];
    int e2 = lane >> 5;
    int sub = lane & 31;
    int head = sub >> 4;
    float adh = asd[(size_t)d * 4 + 2 + head];
    int cbase = sub * 8;
    const unsigned char* hc = h + cbase;
    v2f a01 = {0, 0}, a23 = {0, 0}, a45 = {0, 0}, a67 = {0, 0};
    float den = 0.f;
#pragma unroll 2
    for (int i = beg; i < end; i += 2) {
        int ei = i + e2;
        bool valid = ei < end;
        int s = csr[valid ? ei : end - 1];
        float e = lrelu(asd[(size_t)s * 4 + head] + adh);
        float wgt = valid ? __expf(e) : 0.f;
        den += wgt;
        uint2 u = *(const uint2*)(hc + (size_t)s * C2);
        v2f w2 = {wgt, wgt};
        a01 += w2 * __builtin_amdgcn_cvt_pk_f32_fp8(u.x, false);
        a23 += w2 * __builtin_amdgcn_cvt_pk_f32_fp8(u.x, true);
        a45 += w2 * __builtin_amdgcn_cvt_pk_f32_fp8(u.y, false);
        a67 += w2 * __builtin_amdgcn_cvt_pk_f32_fp8(u.y, true);
    }
    float a[8] = {a01.x, a01.y, a23.x, a23.y, a45.x, a45.y, a67.x, a67.y};
#pragma unroll
    for (int j = 0; j < 8; ++j) a[j] += __shfl_xor(a[j], 32);
    den += __shfl_xor(den, 32);
    if (e2 == 0) {
        // self-loop term (src = d), not present in csr
        float wS = __expf(lrelu(asd[(size_t)d * 4 + head] + adh));
        uint2 u = *(const uint2*)(hc + (size_t)d * C2);
        v2f p0 = __builtin_amdgcn_cvt_pk_f32_fp8(u.x, false);
        v2f p1 = __builtin_amdgcn_cvt_pk_f32_fp8(u.x, true);
        v2f p2 = __builtin_amdgcn_cvt_pk_f32_fp8(u.y, false);
        v2f p3 = __builtin_amdgcn_cvt_pk_f32_fp8(u.y, true);
        a[0] += wS * p0.x; a[1] += wS * p0.y;
        a[2] += wS * p1.x; a[3] += wS * p1.y;
        a[4] += wS * p2.x; a[5] += wS * p2.y;
        a[6] += wS * p3.x; a[7] += wS * p3.y;
        float rden = 1.f / (den + wS + 1e-16f);
        us8 o;
#pragma unroll
        for (int j = 0; j < 8; ++j) o[j] = f2bf(fmaxf(a[j] * rden + bias[cbase + j], 0.f));
        *(us8*)(out + (size_t)d * C2 + cbase) = o;
    }
}

// ---------------- post-MLP fused: t = A@Wp1 + bp1; out = sigmoid(t.Wp2 + bp2) ----------------
template<int G>
__global__ __launch_bounds__(256) void gemm_final(const unsigned short* __restrict__ A,
                                                  const unsigned short* __restrict__ Bp,
                                                  const float* __restrict__ bp1,
                                                  const float* __restrict__ wp2,
                                                  const float* __restrict__ bp2,
                                                  float* __restrict__ out,
                                                  int M, int K) {
    int ksteps = K >> 5;                 // 8
    int mtiles = M >> 4;
    int groups = (mtiles + G - 1) / G;
    int mp = (blockIdx.x << 2) + (threadIdx.x >> 6);
    if (mp >= groups) return;
    int lane = threadIdx.x & 63;
    int l16 = lane & 15, quad = lane >> 4;

    int mrow[G];
#pragma unroll
    for (int gi = 0; gi < G; ++gi) {
        int mt = mp * G + gi;
        mrow[gi] = (mt < mtiles ? mt : mtiles - 1) * 16 + l16;
    }

    const unsigned short* Bf = Bp + lane * 8;
    v4f acc[G][8];
#pragma unroll
    for (int gi = 0; gi < G; ++gi)
#pragma unroll
        for (int t = 0; t < 8; ++t) acc[gi][t] = (v4f){0, 0, 0, 0};
    for (int k0 = 0; k0 < ksteps; ++k0) {
        v8bf a[G];
#pragma unroll
        for (int gi = 0; gi < G; ++gi)
            a[gi] = *(const v8bf*)(A + (size_t)mrow[gi] * K + k0 * 32 + quad * 8);
#pragma unroll
        for (int t = 0; t < 8; ++t) {
            v8bf bfr = *(const v8bf*)(Bf + ((size_t)(t * ksteps + k0) << 9));
#pragma unroll
            for (int gi = 0; gi < G; ++gi)
                acc[gi][t] = __builtin_amdgcn_mfma_f32_16x16x32_bf16(a[gi], bfr, acc[gi][t], 0, 0, 0);
        }
    }
    int cb = l16 * 8;                    // lane's 8 consecutive cols
    float wv8[8], bv[8];
#pragma unroll
    for (int t = 0; t < 8; ++t) {
        wv8[t] = wp2[cb + t];
        bv[t] = bp1[cb + t];
    }
    float bias2 = bp2[0];
#pragma unroll
    for (int gi = 0; gi < G; ++gi) {
        int mt = mp * G + gi;
        if (mt >= mtiles) break;
        int row0 = mt * 16 + quad * 4;
#pragma unroll
        for (int r = 0; r < 4; ++r) {
            float s = 0.f;
#pragma unroll
            for (int t = 0; t < 8; ++t) s += (acc[gi][t][r] + bv[t]) * wv8[t];
#pragma unroll
            for (int off = 8; off; off >>= 1) s += __shfl_xor(s, off);
            if (l16 == 0) {
                float xv = s + bias2;
                out[row0 + r] = 1.f / (1.f + __expf(-xv));
            }
        }
    }
}

extern "C" void kernel_launch(void* const* d_in, const int* in_sizes, int n_in,
                              void* d_out, int out_size, void* d_ws, size_t ws_size,
                              hipStream_t stream) {
    const float* x   = (const float*)d_in[0];
    const int*   ei  = (const int*)d_in[1];
    const float* W1  = (const float*)d_in[2];
    const float* as1 = (const float*)d_in[3];
    const float* ad1 = (const float*)d_in[4];
    const float* b1  = (const float*)d_in[5];
    const float* W2  = (const float*)d_in[6];
    const float* as2 = (const float*)d_in[7];
    const float* ad2 = (const float*)d_in[8];
    const float* b2  = (const float*)d_in[9];
    const float* Wp1 = (const float*)d_in[10];
    const float* bp1 = (const float*)d_in[11];
    const float* Wp2 = (const float*)d_in[12];
    const float* bp2 = (const float*)d_in[13];
    float* out = (float*)d_out;

    int NN = in_sizes[0] / HID;   // 50000
    int E  = in_sizes[1] / 2;     // 800000

    char* ws = (char*)d_ws;
    size_t off = 0;
    auto alloc = [&](size_t bytes) -> char* {
        char* p = ws + off;
        off += (bytes + 255) & ~(size_t)255;
        return p;
    };
    unsigned char*  bufH = (unsigned char*)alloc((size_t)NN * C2);       // h, fp8 e4m3
    unsigned short* bufO = (unsigned short*)alloc((size_t)NN * C2 * 2);  // agg out, bf16
    float* asd = (float*)alloc((size_t)NN * 4 * sizeof(float));
    int* rs    = (int*)alloc((size_t)(NN + 1) * 4);
    int* cnt   = (int*)alloc((size_t)NN * 4);
    int* rank  = (int*)alloc((size_t)E * 4);
    int* csr   = (int*)alloc((size_t)E * 4);
    int* part  = (int*)alloc(1024);
    unsigned short* W1p  = (unsigned short*)alloc((size_t)HID * C2 * 2);  // packed
    unsigned short* W2p  = (unsigned short*)alloc((size_t)C2 * C2 * 2);
    unsigned short* Wp1p = (unsigned short*)alloc((size_t)C2 * HID * 2);

    int nchunk = (NN + 255) / 256;
    int eblk   = (E + 255) / 256;

    // prep: weight packing + hist/rank (fused)
    int pb1 = (HID * C2 / 8 + 255) / 256;
    int pb2 = (C2 * C2 / 8 + 255) / 256;
    int pb3 = (C2 * HID / 8 + 255) / 256;
    hipMemsetAsync(cnt, 0, (size_t)NN * 4, stream);
    prep_kernel<<<pb1 + pb2 + pb3 + eblk, 256, 0, stream>>>(W1, W1p, W2, W2p, Wp1, Wp1p,
                                                            ei, cnt, rank, E, pb1, pb2, pb3);
    scanA<<<nchunk, 256, 0, stream>>>(cnt, rs, part, NN);
    scanB<<<1, 256, 0, stream>>>(part, nchunk);
    scanC<<<nchunk, 256, 0, stream>>>(rs, part, NN, E);

    const int G = 2;
    int mtiles = NN / 16;                     // 3125
    int groups = (mtiles + G - 1) / G;
    int gemmBlocks = (groups * 2 + 3) / 4;    // ngrp=2
    int aggGrid = (NN + 3) / 4;

    // layer 1 (A = fp32 x) + fused alpha dots, scatter piggy-backed
    gemm_alpha<true, G><<<gemmBlocks + eblk, 256, 0, stream>>>(x, W1p, as1, ad1, asd, bufH,
                                                               NN, C2, HID, gemmBlocks,
                                                               ei, rs, rank, csr, E);
    agg_kernel<<<aggGrid, 256, 0, stream>>>(rs, csr, bufH, asd, b1, bufO, NN);
    // layer 2
    gemm_alpha<false, G><<<gemmBlocks, 256, 0, stream>>>(bufO, W2p, as2, ad2, asd, bufH,
                                                         NN, C2, C2, gemmBlocks,
                                                         nullptr, nullptr, nullptr, nullptr, 0);
    agg_kernel<<<aggGrid, 256, 0, stream>>>(rs, csr, bufH, asd, b2, bufO, NN);
    // post-MLP fully fused
    gemm_final<G><<<(groups + 3) / 4, 256, 0, stream>>>(bufO, Wp1p, bp1, Wp2, bp2, out, NN, C2);
}